// Round 11
// baseline (454.771 us; speedup 1.0000x reference)
//
#include <hip/hip_runtime.h>
#include <hip/hip_bf16.h>

#define BATCH 128
#define IN_DIM 512
#define HDIM 1024
#define K2_BCHUNK 8
#define K3_BCHUNK 8

typedef __attribute__((ext_vector_type(4))) float f32x4;

// tanh(x) = 1 - 2/(e^{2x}+1); saturates correctly at +-inf
__device__ __forceinline__ float fast_tanh(float x) {
    float e = __expf(2.0f * x);
    return 1.0f - 2.0f * __builtin_amdgcn_rcpf(e + 1.0f);
}

// K1: emb[b,h] = tanh(items[b,:] . W1[h,:] + b1[h]);  grid=B, block=256
// Block 0 also re-initializes nm_acc[b][j] = bn[j] (atomic accumulators).
__global__ __launch_bounds__(256) void k1_emb(
    const float* __restrict__ items, const float* __restrict__ W1,
    const float* __restrict__ b1, const float* __restrict__ bn,
    float* __restrict__ emb_f, float* __restrict__ nm_acc)
{
    __shared__ float it[IN_DIM];
    int b = blockIdx.x, t = threadIdx.x;
    if (b == 0) nm_acc[t] = bn[t & 1];       // 256 = BATCH*2 entries
    it[t] = items[b * IN_DIM + t];
    it[t + 256] = items[b * IN_DIM + t + 256];
    __syncthreads();
    #pragma unroll
    for (int j = 0; j < 4; ++j) {
        int h = t + 256 * j;
        const float* wrow = W1 + h * IN_DIM;
        float acc = 0.f;
        #pragma unroll 4
        for (int c = 0; c < IN_DIM; c += 4) {
            f32x4 w = *reinterpret_cast<const f32x4*>(wrow + c);
            acc += w[0] * it[c] + w[1] * it[c + 1] + w[2] * it[c + 2] + w[3] * it[c + 3];
        }
        emb_f[b * HDIM + h] = tanhf(acc + b1[h]);
    }
}

// K2: pre[b,h] = b2[h] + sum_i emb[b,i]*(alpha[h,i]*plastic[b,h,i] + W2[h,i])
//     hid[b,h] = tanh(pre).  Wave w owns row h; alpha/W2 rows in registers;
// loops K2_BCHUNK batches. grid = 256 * (B/K2_BCHUNK) = 4096.
__global__ __launch_bounds__(256) void k2_hidden(
    const float* __restrict__ plastic, const float* __restrict__ alpha,
    const float* __restrict__ W2, const float* __restrict__ b2,
    const float* __restrict__ emb_f, float* __restrict__ pre_f,
    float* __restrict__ hid_f)
{
    int hg = blockIdx.x & 255;
    int bg = blockIdx.x >> 8;
    int w  = threadIdx.x >> 6;
    int l  = threadIdx.x & 63;
    int h  = (hg << 2) + w;

    const float* arow = alpha + (h << 10);
    const float* wrow = W2 + (h << 10);
    f32x4 ar[4], wr[4];
    #pragma unroll
    for (int c = 0; c < 4; ++c) {
        int i = c * 256 + l * 4;
        ar[c] = *reinterpret_cast<const f32x4*>(arow + i);
        wr[c] = *reinterpret_cast<const f32x4*>(wrow + i);
    }
    float b2h = b2[h];

    #pragma unroll 2
    for (int bb = 0; bb < K2_BCHUNK; ++bb) {
        int b = bg * K2_BCHUNK + bb;
        const float* prow = plastic + (((size_t)b) << 20) + ((size_t)h << 10);
        const float* erow = emb_f + (b << 10);
        float acc = 0.f;
        #pragma unroll
        for (int c = 0; c < 4; ++c) {
            int i = c * 256 + l * 4;
            f32x4 p = *reinterpret_cast<const f32x4*>(prow + i);
            f32x4 e = *reinterpret_cast<const f32x4*>(erow + i);
            acc += e[0] * fmaf(ar[c][0], p[0], wr[c][0]);
            acc += e[1] * fmaf(ar[c][1], p[1], wr[c][1]);
            acc += e[2] * fmaf(ar[c][2], p[2], wr[c][2]);
            acc += e[3] * fmaf(ar[c][3], p[3], wr[c][3]);
        }
        #pragma unroll
        for (int off = 32; off > 0; off >>= 1) acc += __shfl_xor(acc, off);
        if (l == 0) {
            float pre = acc + b2h;
            pre_f[(b << 10) + h] = pre;
            hid_f[(b << 10) + h] = tanhf(pre);
        }
    }
}

// K3a: t3[b,h] = tanh( sum_i (hid[b,i]+rw*Wr[i]+br[i]) * W3[h,i] + b3[h] )
// folded: nm_acc[b][j] += t3[b,h] * Wn[j][h]. grid = 256 * (B/K3_BCHUNK).
__global__ __launch_bounds__(256) void k3a_nm(
    const float* __restrict__ hid_f, const float* __restrict__ reward,
    const float* __restrict__ Wr, const float* __restrict__ br,
    const float* __restrict__ W3, const float* __restrict__ b3,
    const float* __restrict__ Wn, float* __restrict__ nm_acc)
{
    int hg = blockIdx.x & 255;
    int bg = blockIdx.x >> 8;
    int w  = threadIdx.x >> 6;
    int l  = threadIdx.x & 63;
    int h  = (hg << 2) + w;

    const float* wrow = W3 + (h << 10);
    f32x4 w3r[4], wrr[4], brr[4];
    #pragma unroll
    for (int c = 0; c < 4; ++c) {
        int i = c * 256 + l * 4;
        w3r[c] = *reinterpret_cast<const f32x4*>(wrow + i);
        wrr[c] = *reinterpret_cast<const f32x4*>(Wr + i);
        brr[c] = *reinterpret_cast<const f32x4*>(br + i);
    }
    float b3h = b3[h];
    float wn0 = Wn[h], wn1 = Wn[HDIM + h];

    __shared__ float part[4][K3_BCHUNK][2];

    for (int bb = 0; bb < K3_BCHUNK; ++bb) {
        int b = bg * K3_BCHUNK + bb;
        float rw = reward[b];
        const float* hrow = hid_f + (b << 10);
        float acc = 0.f;
        #pragma unroll
        for (int c = 0; c < 4; ++c) {
            int i = c * 256 + l * 4;
            f32x4 hh = *reinterpret_cast<const f32x4*>(hrow + i);
            #pragma unroll
            for (int j = 0; j < 4; ++j)
                acc += (hh[j] + fmaf(rw, wrr[c][j], brr[c][j])) * w3r[c][j];
        }
        #pragma unroll
        for (int off = 32; off > 0; off >>= 1) acc += __shfl_xor(acc, off);
        if (l == 0) {
            float t3 = tanhf(acc + b3h);
            part[w][bb][0] = t3 * wn0;
            part[w][bb][1] = t3 * wn1;
        }
    }
    __syncthreads();
    int t = threadIdx.x;
    if (t < K3_BCHUNK * 2) {
        int bb = t >> 1, j = t & 1;
        float s = part[0][bb][j] + part[1][bb][j] + part[2][bb][j] + part[3][bb][j];
        atomicAdd(nm_acc + ((bg * K3_BCHUNK + bb) << 1) + j, s);
    }
}

// K4: new_plastic = clip(plastic + nm[b]*tanh(pre[b,h]*emb[b,i])*10, -50, 50)
// Reverse block walk (harvests k2's L3-resident tail). NT LOADS for plastic:
// probe caches (harvest hits still hit) but no allocation on miss, leaving
// L2/L3 to the store stream. NORMAL stores: full-line write-back fast path.
__global__ __launch_bounds__(256) void k4_update(
    const float* __restrict__ plastic, const float* __restrict__ emb_f,
    const float* __restrict__ pre_f, const float* __restrict__ nm_acc,
    float* __restrict__ outp)
{
    const int NBLK = (int)(((size_t)BATCH << 20) / 2048);
    size_t idx = ((size_t)(NBLK - 1 - (int)blockIdx.x)) * 2048 + (size_t)threadIdx.x * 8;
    int b   = (int)(idx >> 20);
    int rem = (int)(idx & 1048575u);
    int h   = rem >> 10;
    int i0  = rem & 1023;
    float nm  = fast_tanh(nm_acc[2 * b]) - fast_tanh(nm_acc[2 * b + 1]);
    float pre = pre_f[(b << 10) + h];
    f32x4 p0 = __builtin_nontemporal_load(reinterpret_cast<const f32x4*>(plastic + idx));
    f32x4 p1 = __builtin_nontemporal_load(reinterpret_cast<const f32x4*>(plastic + idx + 4));
    f32x4 e0 = *reinterpret_cast<const f32x4*>(emb_f + (b << 10) + i0);
    f32x4 e1 = *reinterpret_cast<const f32x4*>(emb_f + (b << 10) + i0 + 4);
    f32x4 o0, o1;
    #pragma unroll
    for (int j = 0; j < 4; ++j) {
        float v0 = fmaf(nm, fast_tanh(pre * e0[j]) * 10.0f, p0[j]);
        float v1 = fmaf(nm, fast_tanh(pre * e1[j]) * 10.0f, p1[j]);
        o0[j] = fminf(fmaxf(v0, -50.0f), 50.0f);
        o1[j] = fminf(fmaxf(v1, -50.0f), 50.0f);
    }
    *reinterpret_cast<f32x4*>(outp + idx)     = o0;
    *reinterpret_cast<f32x4*>(outp + idx + 4) = o1;
}

// K3c: once at end: choice, value, nm output, hidden output. grid=B.
__global__ __launch_bounds__(256) void k3c_heads(
    const float* __restrict__ hid_f, const float* __restrict__ nm_acc,
    const float* __restrict__ Wc, const float* __restrict__ bc,
    const float* __restrict__ Wv, const float* __restrict__ bv,
    float* __restrict__ out)
{
    int b = blockIdx.x, t = threadIdx.x;
    int w = t >> 6, l = t & 63;
    const float* hrow = hid_f + (b << 10);
    if (w < 2) {
        const float* wv = (w == 0) ? Wc : Wv;
        float acc = 0.f;
        #pragma unroll
        for (int c = 0; c < 4; ++c) {
            int i = c * 256 + l * 4;
            f32x4 wg = *reinterpret_cast<const f32x4*>(wv + i);
            f32x4 ss = *reinterpret_cast<const f32x4*>(hrow + i);
            acc += ss[0] * wg[0] + ss[1] * wg[1] + ss[2] * wg[2] + ss[3] * wg[3];
        }
        #pragma unroll
        for (int off = 32; off > 0; off >>= 1) acc += __shfl_xor(acc, off);
        if (l == 0) {
            if (w == 0) out[b] = 1.0f / (1.0f + __expf(-(acc + bc[0])));  // choice
            else        out[2 * BATCH + b] = acc + bv[0];                 // value
        }
    } else if (t == 128) {
        out[BATCH + b] = tanhf(nm_acc[2 * b]) - tanhf(nm_acc[2 * b + 1]); // nm
    }
    const size_t HID_OFF = (size_t)3 * BATCH + (size_t)BATCH * HDIM * HDIM;
    for (int i = t; i < HDIM; i += 256)
        out[HID_OFF + (size_t)b * HDIM + i] = hrow[i];
}

extern "C" void kernel_launch(void* const* d_in, const int* in_sizes, int n_in,
                              void* d_out, int out_size, void* d_ws, size_t ws_size,
                              hipStream_t stream)
{
    const float* items   = (const float*)d_in[0];
    const float* plastic = (const float*)d_in[1];
    const float* reward  = (const float*)d_in[2];
    const float* W1 = (const float*)d_in[3];
    const float* b1 = (const float*)d_in[4];
    const float* W2 = (const float*)d_in[5];
    const float* b2 = (const float*)d_in[6];
    const float* W3 = (const float*)d_in[7];
    const float* b3 = (const float*)d_in[8];
    const float* Wc = (const float*)d_in[9];
    const float* bc = (const float*)d_in[10];
    const float* Wr = (const float*)d_in[11];
    const float* br = (const float*)d_in[12];
    const float* Wn = (const float*)d_in[13];
    const float* bn = (const float*)d_in[14];
    const float* alpha = (const float*)d_in[15];
    const float* Wv = (const float*)d_in[16];
    const float* bv = (const float*)d_in[17];

    float* ws     = (float*)d_ws;
    float* emb_f  = ws;                // 131072 floats
    float* pre_f  = ws + 131072;       // 131072
    float* hid_f  = ws + 262144;       // 131072
    float* nm_acc = ws + 393216;       // 256

    float* out  = (float*)d_out;
    float* outp = out + 384;           // new_plastic after choice/nm/value

    k1_emb   <<<BATCH, 256, 0, stream>>>(items, W1, b1, bn, emb_f, nm_acc);
    k2_hidden<<<256 * (BATCH / K2_BCHUNK), 256, 0, stream>>>(
        plastic, alpha, W2, b2, emb_f, pre_f, hid_f);
    k3a_nm   <<<256 * (BATCH / K3_BCHUNK), 256, 0, stream>>>(
        hid_f, reward, Wr, br, W3, b3, Wn, nm_acc);
    k4_update<<<(int)(((size_t)BATCH << 20) / 2048), 256, 0, stream>>>(
        plastic, emb_f, pre_f, nm_acc, outp);
    k3c_heads<<<BATCH, 256, 0, stream>>>(hid_f, nm_acc, Wc, bc, Wv, bv, out);
}

// Round 12
// 403.304 us; speedup vs baseline: 1.1276x; 1.1276x over previous
//
#include <hip/hip_runtime.h>
#include <hip/hip_bf16.h>

#define BATCH 128
#define IN_DIM 512
#define HDIM 1024
#define K2_BCHUNK 8
#define K3_BCHUNK 8

typedef __attribute__((ext_vector_type(4))) float f32x4;

// tanh(x) = 1 - 2/(e^{2x}+1); saturates correctly at +-inf
__device__ __forceinline__ float fast_tanh(float x) {
    float e = __expf(2.0f * x);
    return 1.0f - 2.0f * __builtin_amdgcn_rcpf(e + 1.0f);
}

// K1: emb[b,h] = tanh(items[b,:] . W1[h,:] + b1[h]);  grid=B, block=256
// Block 0 also re-initializes nm_acc[b][j] = bn[j] (atomic accumulators).
__global__ __launch_bounds__(256) void k1_emb(
    const float* __restrict__ items, const float* __restrict__ W1,
    const float* __restrict__ b1, const float* __restrict__ bn,
    float* __restrict__ emb_f, float* __restrict__ nm_acc)
{
    __shared__ float it[IN_DIM];
    int b = blockIdx.x, t = threadIdx.x;
    if (b == 0) nm_acc[t] = bn[t & 1];       // 256 = BATCH*2 entries
    it[t] = items[b * IN_DIM + t];
    it[t + 256] = items[b * IN_DIM + t + 256];
    __syncthreads();
    #pragma unroll
    for (int j = 0; j < 4; ++j) {
        int h = t + 256 * j;
        const float* wrow = W1 + h * IN_DIM;
        float acc = 0.f;
        #pragma unroll 4
        for (int c = 0; c < IN_DIM; c += 4) {
            f32x4 w = *reinterpret_cast<const f32x4*>(wrow + c);
            acc += w[0] * it[c] + w[1] * it[c + 1] + w[2] * it[c + 2] + w[3] * it[c + 3];
        }
        emb_f[b * HDIM + h] = tanhf(acc + b1[h]);
    }
}

// K2: pre[b,h] = b2[h] + sum_i emb[b,i]*(alpha[h,i]*plastic[b,h,i] + W2[h,i])
//     hid[b,h] = tanh(pre).  Wave w owns row h; alpha/W2 rows in registers;
// loops K2_BCHUNK batches. grid = 256 * (B/K2_BCHUNK) = 4096.
__global__ __launch_bounds__(256) void k2_hidden(
    const float* __restrict__ plastic, const float* __restrict__ alpha,
    const float* __restrict__ W2, const float* __restrict__ b2,
    const float* __restrict__ emb_f, float* __restrict__ pre_f,
    float* __restrict__ hid_f)
{
    int hg = blockIdx.x & 255;
    int bg = blockIdx.x >> 8;
    int w  = threadIdx.x >> 6;
    int l  = threadIdx.x & 63;
    int h  = (hg << 2) + w;

    const float* arow = alpha + (h << 10);
    const float* wrow = W2 + (h << 10);
    f32x4 ar[4], wr[4];
    #pragma unroll
    for (int c = 0; c < 4; ++c) {
        int i = c * 256 + l * 4;
        ar[c] = *reinterpret_cast<const f32x4*>(arow + i);
        wr[c] = *reinterpret_cast<const f32x4*>(wrow + i);
    }
    float b2h = b2[h];

    #pragma unroll 2
    for (int bb = 0; bb < K2_BCHUNK; ++bb) {
        int b = bg * K2_BCHUNK + bb;
        const float* prow = plastic + (((size_t)b) << 20) + ((size_t)h << 10);
        const float* erow = emb_f + (b << 10);
        float acc = 0.f;
        #pragma unroll
        for (int c = 0; c < 4; ++c) {
            int i = c * 256 + l * 4;
            f32x4 p = *reinterpret_cast<const f32x4*>(prow + i);
            f32x4 e = *reinterpret_cast<const f32x4*>(erow + i);
            acc += e[0] * fmaf(ar[c][0], p[0], wr[c][0]);
            acc += e[1] * fmaf(ar[c][1], p[1], wr[c][1]);
            acc += e[2] * fmaf(ar[c][2], p[2], wr[c][2]);
            acc += e[3] * fmaf(ar[c][3], p[3], wr[c][3]);
        }
        #pragma unroll
        for (int off = 32; off > 0; off >>= 1) acc += __shfl_xor(acc, off);
        if (l == 0) {
            float pre = acc + b2h;
            pre_f[(b << 10) + h] = pre;
            hid_f[(b << 10) + h] = tanhf(pre);
        }
    }
}

// K3a: t3[b,h] = tanh( sum_i (hid[b,i]+rw*Wr[i]+br[i]) * W3[h,i] + b3[h] )
// folded: nm_acc[b][j] += t3[b,h] * Wn[j][h]. grid = 256 * (B/K3_BCHUNK).
__global__ __launch_bounds__(256) void k3a_nm(
    const float* __restrict__ hid_f, const float* __restrict__ reward,
    const float* __restrict__ Wr, const float* __restrict__ br,
    const float* __restrict__ W3, const float* __restrict__ b3,
    const float* __restrict__ Wn, float* __restrict__ nm_acc)
{
    int hg = blockIdx.x & 255;
    int bg = blockIdx.x >> 8;
    int w  = threadIdx.x >> 6;
    int l  = threadIdx.x & 63;
    int h  = (hg << 2) + w;

    const float* wrow = W3 + (h << 10);
    f32x4 w3r[4], wrr[4], brr[4];
    #pragma unroll
    for (int c = 0; c < 4; ++c) {
        int i = c * 256 + l * 4;
        w3r[c] = *reinterpret_cast<const f32x4*>(wrow + i);
        wrr[c] = *reinterpret_cast<const f32x4*>(Wr + i);
        brr[c] = *reinterpret_cast<const f32x4*>(br + i);
    }
    float b3h = b3[h];
    float wn0 = Wn[h], wn1 = Wn[HDIM + h];

    __shared__ float part[4][K3_BCHUNK][2];

    for (int bb = 0; bb < K3_BCHUNK; ++bb) {
        int b = bg * K3_BCHUNK + bb;
        float rw = reward[b];
        const float* hrow = hid_f + (b << 10);
        float acc = 0.f;
        #pragma unroll
        for (int c = 0; c < 4; ++c) {
            int i = c * 256 + l * 4;
            f32x4 hh = *reinterpret_cast<const f32x4*>(hrow + i);
            #pragma unroll
            for (int j = 0; j < 4; ++j)
                acc += (hh[j] + fmaf(rw, wrr[c][j], brr[c][j])) * w3r[c][j];
        }
        #pragma unroll
        for (int off = 32; off > 0; off >>= 1) acc += __shfl_xor(acc, off);
        if (l == 0) {
            float t3 = tanhf(acc + b3h);
            part[w][bb][0] = t3 * wn0;
            part[w][bb][1] = t3 * wn1;
        }
    }
    __syncthreads();
    int t = threadIdx.x;
    if (t < K3_BCHUNK * 2) {
        int bb = t >> 1, j = t & 1;
        float s = part[0][bb][j] + part[1][bb][j] + part[2][bb][j] + part[3][bb][j];
        atomicAdd(nm_acc + ((bg * K3_BCHUNK + bb) << 1) + j, s);
    }
}

// K4: new_plastic = clip(plastic + nm[b]*tanh(pre[b,h]*emb[b,i])*10, -50, 50)
// R5 optimum: flat 8 floats/thread, block-granularity reverse walk, NORMAL
// cached loads for plastic, NT stores for the output stream (measured best:
// 404 vs 422 normal/normal vs 455 NT-load/normal-store).
__global__ __launch_bounds__(256) void k4_update(
    const float* __restrict__ plastic, const float* __restrict__ emb_f,
    const float* __restrict__ pre_f, const float* __restrict__ nm_acc,
    float* __restrict__ outp)
{
    const int NBLK = (int)(((size_t)BATCH << 20) / 2048);
    size_t idx = ((size_t)(NBLK - 1 - (int)blockIdx.x)) * 2048 + (size_t)threadIdx.x * 8;
    int b   = (int)(idx >> 20);
    int rem = (int)(idx & 1048575u);
    int h   = rem >> 10;
    int i0  = rem & 1023;
    float nm  = fast_tanh(nm_acc[2 * b]) - fast_tanh(nm_acc[2 * b + 1]);
    float pre = pre_f[(b << 10) + h];
    f32x4 p0 = *reinterpret_cast<const f32x4*>(plastic + idx);
    f32x4 p1 = *reinterpret_cast<const f32x4*>(plastic + idx + 4);
    f32x4 e0 = *reinterpret_cast<const f32x4*>(emb_f + (b << 10) + i0);
    f32x4 e1 = *reinterpret_cast<const f32x4*>(emb_f + (b << 10) + i0 + 4);
    f32x4 o0, o1;
    #pragma unroll
    for (int j = 0; j < 4; ++j) {
        float v0 = fmaf(nm, fast_tanh(pre * e0[j]) * 10.0f, p0[j]);
        float v1 = fmaf(nm, fast_tanh(pre * e1[j]) * 10.0f, p1[j]);
        o0[j] = fminf(fmaxf(v0, -50.0f), 50.0f);
        o1[j] = fminf(fmaxf(v1, -50.0f), 50.0f);
    }
    __builtin_nontemporal_store(o0, reinterpret_cast<f32x4*>(outp + idx));
    __builtin_nontemporal_store(o1, reinterpret_cast<f32x4*>(outp + idx + 4));
}

// K3c: once at end: choice, value, nm output, hidden output. grid=B.
__global__ __launch_bounds__(256) void k3c_heads(
    const float* __restrict__ hid_f, const float* __restrict__ nm_acc,
    const float* __restrict__ Wc, const float* __restrict__ bc,
    const float* __restrict__ Wv, const float* __restrict__ bv,
    float* __restrict__ out)
{
    int b = blockIdx.x, t = threadIdx.x;
    int w = t >> 6, l = t & 63;
    const float* hrow = hid_f + (b << 10);
    if (w < 2) {
        const float* wv = (w == 0) ? Wc : Wv;
        float acc = 0.f;
        #pragma unroll
        for (int c = 0; c < 4; ++c) {
            int i = c * 256 + l * 4;
            f32x4 wg = *reinterpret_cast<const f32x4*>(wv + i);
            f32x4 ss = *reinterpret_cast<const f32x4*>(hrow + i);
            acc += ss[0] * wg[0] + ss[1] * wg[1] + ss[2] * wg[2] + ss[3] * wg[3];
        }
        #pragma unroll
        for (int off = 32; off > 0; off >>= 1) acc += __shfl_xor(acc, off);
        if (l == 0) {
            if (w == 0) out[b] = 1.0f / (1.0f + __expf(-(acc + bc[0])));  // choice
            else        out[2 * BATCH + b] = acc + bv[0];                 // value
        }
    } else if (t == 128) {
        out[BATCH + b] = tanhf(nm_acc[2 * b]) - tanhf(nm_acc[2 * b + 1]); // nm
    }
    const size_t HID_OFF = (size_t)3 * BATCH + (size_t)BATCH * HDIM * HDIM;
    for (int i = t; i < HDIM; i += 256)
        out[HID_OFF + (size_t)b * HDIM + i] = hrow[i];
}

extern "C" void kernel_launch(void* const* d_in, const int* in_sizes, int n_in,
                              void* d_out, int out_size, void* d_ws, size_t ws_size,
                              hipStream_t stream)
{
    const float* items   = (const float*)d_in[0];
    const float* plastic = (const float*)d_in[1];
    const float* reward  = (const float*)d_in[2];
    const float* W1 = (const float*)d_in[3];
    const float* b1 = (const float*)d_in[4];
    const float* W2 = (const float*)d_in[5];
    const float* b2 = (const float*)d_in[6];
    const float* W3 = (const float*)d_in[7];
    const float* b3 = (const float*)d_in[8];
    const float* Wc = (const float*)d_in[9];
    const float* bc = (const float*)d_in[10];
    const float* Wr = (const float*)d_in[11];
    const float* br = (const float*)d_in[12];
    const float* Wn = (const float*)d_in[13];
    const float* bn = (const float*)d_in[14];
    const float* alpha = (const float*)d_in[15];
    const float* Wv = (const float*)d_in[16];
    const float* bv = (const float*)d_in[17];

    float* ws     = (float*)d_ws;
    float* emb_f  = ws;                // 131072 floats
    float* pre_f  = ws + 131072;       // 131072
    float* hid_f  = ws + 262144;       // 131072
    float* nm_acc = ws + 393216;       // 256

    float* out  = (float*)d_out;
    float* outp = out + 384;           // new_plastic after choice/nm/value

    k1_emb   <<<BATCH, 256, 0, stream>>>(items, W1, b1, bn, emb_f, nm_acc);
    k2_hidden<<<256 * (BATCH / K2_BCHUNK), 256, 0, stream>>>(
        plastic, alpha, W2, b2, emb_f, pre_f, hid_f);
    k3a_nm   <<<256 * (BATCH / K3_BCHUNK), 256, 0, stream>>>(
        hid_f, reward, Wr, br, W3, b3, Wn, nm_acc);
    k4_update<<<(int)(((size_t)BATCH << 20) / 2048), 256, 0, stream>>>(
        plastic, emb_f, pre_f, nm_acc, outp);
    k3c_heads<<<BATCH, 256, 0, stream>>>(hid_f, nm_acc, Wc, bc, Wv, bv, out);
}